// Round 14
// baseline (677.173 us; speedup 1.0000x reference)
//
#include <hip/hip_runtime.h>
#include <hip/hip_bf16.h>

// LoRA transformer: L=8, D=1024, H=16, HD=64, R=16, B=2, S=1024.
// bf16 MFMA everywhere, fp32 residual stream.
// R11: vtrans fused into qkv-GEMM epilogue. R12: merge_T2 W tile via DMA,
// LOG2E folded into Q pre-scale. R14: qkv 64x128 tile, 768 blocks (3/CU).
// R15/R17: attn swapped QK^T, scalar m/l, defer-max, packed P LDS round-trip.
// R19: attn KVBLK=128. R20: proj BK=128 (kept); merge 4-way split (REVERTED:
// +11us of dispatch tails; top-5 visibility unattainable anyway - harness
// fill kernels at 58us own all slots).
// R21: T4 counted-vmcnt in all three loop kernels: __syncthreads (which
// drains vmcnt(0), killing the dbuf prefetch - m97's ~20% stall) replaced by
// raw s_barrier pairs with s_waitcnt vmcnt(N) counted per stage (6 for qkv,
// 8 for proj/attn). Prefetch stays in flight across the barrier (m218:
// counted-vs-drain0 = +38-73% on GEMM). sched_barrier(0) fences per rule 18.

typedef unsigned short ushort_t;
typedef __attribute__((ext_vector_type(8))) short bf16x8;
typedef __attribute__((ext_vector_type(4))) float f32x4;
typedef __attribute__((ext_vector_type(2))) unsigned int uint32x2;

__device__ __forceinline__ unsigned short f2bf(float f) {
    union { float f; unsigned int u; } x; x.f = f;
    unsigned int r = x.u + 0x7fffu + ((x.u >> 16) & 1u);  // RNE
    return (unsigned short)(r >> 16);
}

// single-instruction bf16 convert (RNE), result in low 16 bits
__device__ __forceinline__ unsigned short f2bf_fast(float f) {
    unsigned int r;
    asm("v_cvt_pk_bf16_f32 %0, %1, %2" : "=v"(r) : "v"(f), "v"(0.f));
    return (unsigned short)r;
}

// pack two f32 -> {bf16(lo), bf16(hi)} in one dword
__device__ __forceinline__ unsigned int cvtpk(float lo, float hi) {
    unsigned int r;
    asm("v_cvt_pk_bf16_f32 %0, %1, %2" : "=v"(r) : "v"(lo), "v"(hi));
    return r;
}

__device__ __forceinline__ f32x4 mfma16(bf16x8 a, bf16x8 b, f32x4 c) {
    return __builtin_amdgcn_mfma_f32_16x16x32_bf16(a, b, c, 0, 0, 0);
}

typedef const __attribute__((address_space(1))) unsigned int* gas_ptr;
typedef __attribute__((address_space(3))) unsigned int* las_ptr;
// async global->LDS, 16B/lane; LDS dest = wave-uniform base + lane*16 (m104/m108)
__device__ __forceinline__ void lds_stage16(const void* g, void* l) {
    __builtin_amdgcn_global_load_lds((gas_ptr)(unsigned long long)g,
                                     (las_ptr)(unsigned int)(unsigned long long)l,
                                     16, 0, 0);
}

// ---- T4 counted-vmcnt primitives (rule 18: sched_barrier fences) ----
template <int N>
__device__ __forceinline__ void wait_vmcnt() {
    if constexpr (N == 0)      asm volatile("s_waitcnt vmcnt(0)" ::: "memory");
    else if constexpr (N == 6) asm volatile("s_waitcnt vmcnt(6)" ::: "memory");
    else                       asm volatile("s_waitcnt vmcnt(8)" ::: "memory");
}
__device__ __forceinline__ void hard_barrier() {
    __builtin_amdgcn_sched_barrier(0);
    __builtin_amdgcn_s_barrier();
    __builtin_amdgcn_sched_barrier(0);
}
__device__ __forceinline__ void lgkm_drain() {
    asm volatile("s_waitcnt lgkmcnt(0)" ::: "memory");
}

// ---------------- x -> (h_f32 copy, h_bf16) ----------------
__global__ __launch_bounds__(256) void convert_x(
    const float4* __restrict__ in, float4* __restrict__ outF,
    ushort4* __restrict__ outB, int n4) {
    int i = blockIdx.x * 256 + threadIdx.x;
    if (i < n4) {
        float4 v = in[i];
        outF[i] = v;
        ushort4 o;
        o.x = f2bf(v.x); o.y = f2bf(v.y); o.z = f2bf(v.z); o.w = f2bf(v.w);
        outB[i] = o;
    }
}

// ------------- LoRA merge + transpose, qkv + proj in ONE dispatch -------------
// blocks 0..6143: qkv (24x32x8); blocks 6144..8191: proj (8x32x8)
// WT[z][n][k] = bf16(W[z][k][n] + A[z][k][:] . B[z][:][n])
// W tile -> LDS via DMA; lora computed in transposed layout; B column in regs.
__global__ __launch_bounds__(256) void merge_T2(
    const float* __restrict__ Wq, const float* __restrict__ Aq,
    const float* __restrict__ Bq, unsigned short* __restrict__ WTq,
    const float* __restrict__ Wp, const float* __restrict__ Ap,
    const float* __restrict__ Bp, unsigned short* __restrict__ WTp) {
    __shared__ float Asl[32][17];                 // A tile (32 rows x 16), +1 pad
    __shared__ __align__(16) float tW[32 * 128];  // W tile, DMA'd, linear
    int bid = blockIdx.x;
    const float *W, *A, *Bm;
    unsigned short* WT;
    int N, bx, by, bz;
    if (bid < 6144) {
        N = 3072; bx = bid % 24; int u = bid / 24; by = u & 31; bz = u >> 5;
        W = Wq; A = Aq; Bm = Bq; WT = WTq;
    } else {
        bid -= 6144;
        N = 1024; bx = bid & 7; int u = bid >> 3; by = u & 31; bz = u >> 5;
        W = Wp; A = Ap; Bm = Bp; WT = WTp;
    }
    W  += (size_t)bz * 1024 * N;
    A  += (size_t)bz * 1024 * 16;
    Bm += (size_t)bz * 16 * N;
    WT += (size_t)bz * N * 1024;
    const int j0 = bx * 128, i0 = by * 32;
    const int tid = threadIdx.x;
    const int w = tid >> 6, lane = tid & 63;

    // DMA W tile (32x128 f32 = 16KB) -> LDS. 4 stage16 per thread.
    #pragma unroll
    for (int s = 0; s < 4; s++) {
        int w4s = w * 4 + s;
        int tr = w4s * 2 + (lane >> 5);
        lds_stage16(W + (size_t)(i0 + tr) * N + j0 + (lane & 31) * 4,
                    (char*)tW + w4s * 1024);
    }
    // Stage A tile cooperatively: 512 floats, 128 threads x float4, coalesced.
    if (tid < 128) {
        int r = tid >> 2, c4 = (tid & 3) * 4;
        float4 a = *(const float4*)&A[(size_t)(i0 + r) * 16 + c4];
        Asl[r][c4 + 0] = a.x; Asl[r][c4 + 1] = a.y;
        Asl[r][c4 + 2] = a.z; Asl[r][c4 + 3] = a.w;
    }
    // B column for this thread's output row: 16 independent dwords, L2-hot.
    const int jj = tid >> 1, half = tid & 1;
    float bcol[16];
    #pragma unroll
    for (int r = 0; r < 16; r++)
        bcol[r] = Bm[(size_t)r * N + j0 + jj];
    __builtin_amdgcn_sched_barrier(0);
    __syncthreads();  // drains W DMA (vmcnt) + A stage

    // 16 output values: rows i0+half*16+c, col j0+jj; transposed store.
    bf16x8 o0, o1;
    #pragma unroll
    for (int c = 0; c < 16; c++) {
        int rloc = half * 16 + c;
        float v = tW[rloc * 128 + jj];             // bank=jj%32: 2-way, free
        #pragma unroll
        for (int r = 0; r < 16; r++)
            v += Asl[rloc][r] * bcol[r];           // Asl: 2-addr broadcast
        unsigned short b = f2bf(v);
        if (c < 8) o0[c] = (short)b; else o1[c - 8] = (short)b;
    }
    unsigned short* dst = &WT[(size_t)(j0 + jj) * 1024 + i0 + half * 16];
    *(bf16x8*)dst = o0;
    *(bf16x8*)(dst + 8) = o1;
}

// --- qkv GEMM: 64x128 tile, dbuf BK=64, counted vmcnt(6); 768 blocks (3/CU) ---
// V-blocks (n0>=2048) write VT transposed directly.
__global__ __launch_bounds__(256) void gemm_qkv(
    const unsigned short* __restrict__ A,   // [M][K] h_bf
    const unsigned short* __restrict__ BT,  // [N][K] merged qkv weights^T
    unsigned short* __restrict__ outB,      // bf16 out (Q,K regions)
    unsigned short* __restrict__ VT,        // [32][64][1024] transposed V out
    int M, int N, int K) {
    __shared__ __align__(16) unsigned short As[2][2][64 * 32];   // [buf][h]
    __shared__ __align__(16) unsigned short Bs[2][2][128 * 32];  // [buf][h]
    const int tid = threadIdx.x;
    const int m0 = blockIdx.y * 64, n0 = blockIdx.x * 128;
    const int w = tid >> 6, lane = tid & 63;
    const int wm = (w >> 1) * 32, wn = (w & 1) * 64;
    const int lr = lane & 15, quad = lane >> 4;
    const int srowA = w * 16 + (lane >> 2);
    const int skof = (lane & 3) * 8;

    f32x4 acc[2][4] = {};

    auto stage = [&](int k0, int buf) {  // 6 loads/thread
        #pragma unroll
        for (int h = 0; h < 2; h++) {
            lds_stage16(A + (size_t)(m0 + srowA) * K + k0 + h * 32 + skof,
                        (char*)As[buf][h] + w * 1024);
            #pragma unroll
            for (int s = 0; s < 2; s++) {
                int srowB = w * 32 + s * 16 + (lane >> 2);
                lds_stage16(BT + (size_t)(n0 + srowB) * K + k0 + h * 32 + skof,
                            (char*)Bs[buf][h] + (w * 2 + s) * 1024);
            }
        }
    };

    const int nk = K >> 6;
    stage(0, 0);
    for (int t = 0; t < nk; t++) {
        if (t + 1 < nk) { stage((t + 1) << 6, (t + 1) & 1); wait_vmcnt<6>(); }
        else wait_vmcnt<0>();
        hard_barrier();  // all waves' stage(t) landed; prefetch in flight
        const int cur = t & 1;
        #pragma unroll
        for (int h = 0; h < 2; h++) {
            bf16x8 af[2], bfr[4];
            #pragma unroll
            for (int i = 0; i < 2; i++)
                af[i] = *(const bf16x8*)&As[cur][h][(wm + i * 16 + lr) * 32 + quad * 8];
            #pragma unroll
            for (int j = 0; j < 4; j++)
                bfr[j] = *(const bf16x8*)&Bs[cur][h][(wn + j * 16 + lr) * 32 + quad * 8];
            #pragma unroll
            for (int i = 0; i < 2; i++)
                #pragma unroll
                for (int j = 0; j < 4; j++)
                    acc[i][j] = mfma16(af[i], bfr[j], acc[i][j]);
        }
        lgkm_drain();
        hard_barrier();  // all reads of buf cur done before next overwrite
    }
    if (n0 < 2048) {  // Q,K regions -> qkv_bf (Q cols pre-scaled by log2e/8)
        #pragma unroll
        for (int i = 0; i < 2; i++)
            #pragma unroll
            for (int j = 0; j < 4; j++)
                #pragma unroll
                for (int r = 0; r < 4; r++) {
                    int row = m0 + wm + i * 16 + quad * 4 + r;
                    int col = n0 + wn + j * 16 + lr;
                    float v = acc[i][j][r];
                    if (col < 1024) v *= 0.125f * 1.44269504f;  // 1/sqrt(64)*log2e
                    outB[(size_t)row * N + col] = f2bf(v);
                }
    } else {  // V region -> VT[b*1024+hd][s], 4 consecutive s per thread
        const int b = m0 >> 10;
        #pragma unroll
        for (int i = 0; i < 2; i++) {
            int row0 = m0 + wm + i * 16 + quad * 4;
            int s = row0 & 1023;
            #pragma unroll
            for (int j = 0; j < 4; j++) {
                int hd = n0 - 2048 + wn + j * 16 + lr;
                ushort4 o;
                o.x = f2bf(acc[i][j][0]); o.y = f2bf(acc[i][j][1]);
                o.z = f2bf(acc[i][j][2]); o.w = f2bf(acc[i][j][3]);
                *(ushort4*)&VT[((size_t)b * 1024 + hd) * 1024 + s] = o;
            }
        }
    }
}

// ----- GEMM 64x64 + residual: dbuf BK=128, counted vmcnt(8), raw barriers -----
__global__ __launch_bounds__(256) void gemm_bf16_64(
    const unsigned short* __restrict__ A,   // [M][K]
    const unsigned short* __restrict__ BT,  // [N][K]
    const float* __restrict__ res,          // [M][N] residual
    float* __restrict__ outF,               // fp32 out
    unsigned short* __restrict__ outB,      // bf16 out
    int M, int N, int K) {
    __shared__ __align__(16) unsigned short As[2][4][64 * 32];  // [buf][k32]
    __shared__ __align__(16) unsigned short Bs[2][4][64 * 32];
    const int tid = threadIdx.x;
    const int m0 = blockIdx.y * 64, n0 = blockIdx.x * 64;
    const int w = tid >> 6, lane = tid & 63;
    const int wm = (w >> 1) * 32, wn = (w & 1) * 32;
    const int lr = lane & 15, quad = lane >> 4;
    const int srow = w * 16 + (lane >> 2);
    const int skof = (lane & 3) * 8;

    f32x4 acc[2][2] = {};

    auto stage = [&](int k0, int buf) {  // 8 loads/thread
        #pragma unroll
        for (int h = 0; h < 4; h++) {
            lds_stage16(A  + (size_t)(m0 + srow) * K + k0 + h * 32 + skof,
                        (char*)As[buf][h] + w * 1024);
            lds_stage16(BT + (size_t)(n0 + srow) * K + k0 + h * 32 + skof,
                        (char*)Bs[buf][h] + w * 1024);
        }
    };

    const int nk = K >> 7;  // 128-k tiles
    stage(0, 0);
    for (int t = 0; t < nk; t++) {
        if (t + 1 < nk) { stage((t + 1) << 7, (t + 1) & 1); wait_vmcnt<8>(); }
        else wait_vmcnt<0>();
        hard_barrier();
        const int cur = t & 1;
        #pragma unroll
        for (int h = 0; h < 4; h++) {
            bf16x8 af[2], bfr[2];
            #pragma unroll
            for (int i = 0; i < 2; i++) {
                af[i]  = *(const bf16x8*)&As[cur][h][(wm + i * 16 + lr) * 32 + quad * 8];
                bfr[i] = *(const bf16x8*)&Bs[cur][h][(wn + i * 16 + lr) * 32 + quad * 8];
            }
            #pragma unroll
            for (int i = 0; i < 2; i++)
                #pragma unroll
                for (int j = 0; j < 2; j++)
                    acc[i][j] = mfma16(af[i], bfr[j], acc[i][j]);
        }
        lgkm_drain();
        hard_barrier();
    }
    #pragma unroll
    for (int i = 0; i < 2; i++)
        #pragma unroll
        for (int j = 0; j < 2; j++)
            #pragma unroll
            for (int r = 0; r < 4; r++) {
                int row = m0 + wm + i * 16 + quad * 4 + r;
                int col = n0 + wn + j * 16 + lr;
                float v = acc[i][j][r] + res[(size_t)row * N + col];
                if (outF) outF[(size_t)row * N + col] = v;
                if (outB) outB[(size_t)row * N + col] = f2bf(v);
            }
}

// -- Flash attention: dbuf DMA staging, KVBLK=128, counted vmcnt(8) barriers --
// 512 blocks, one 64-row q-block each; qblk = bh<16 ? x : 15-x.
// Scores arrive already in log2 domain (Q pre-scaled by log2e/8 in gemm_qkv).
// Swapped QK^T: s = mfma(K,Q) = S^T; lane owns q = qb+lr, k = nh*16+quad*4+r.
// P repack via packed per-wave LDS round-trip, PV in two 64-halves.
__global__ __launch_bounds__(256) void attn_kernel(
    const unsigned short* __restrict__ qkv,  // [2048][3072]
    const unsigned short* __restrict__ VT,   // [32][64][1024]
    unsigned short* __restrict__ O) {        // [2048][1024]
    __shared__ __align__(16) unsigned short Ks[2][2][128 * 32];  // [buf][dhalf][row][d32]
    __shared__ __align__(16) unsigned short Vs[2][4][64 * 32];   // [buf][squarter][d][s32]
    __shared__ __align__(16) unsigned short pls[4][16 * 72];     // P half-rows, stride 72
    const int tid = threadIdx.x;
    const int w = tid >> 6, lane = tid & 63;
    const int lr = lane & 15, quad = lane >> 4;
    const int bh = blockIdx.y, b = bh >> 4, h = bh & 15;
    const int qblk = (bh < 16) ? blockIdx.x : (15 - blockIdx.x);
    const int qb = qblk * 64 + w * 16;
    const int srow = w * 16 + (lane >> 2);
    const int skof = (lane & 3) * 8;

    const size_t rowQ = (size_t)(b * 1024 + qb + lr) * 3072 + h * 64;
    bf16x8 aq0 = *(const bf16x8*)&qkv[rowQ + quad * 8];
    bf16x8 aq1 = *(const bf16x8*)&qkv[rowQ + 32 + quad * 8];

    float m_i = -1e30f, l_i = 0.f;   // scalars: lane owns one q-row (q = qb+lr)
    f32x4 oacc[4] = {};

    // Stage one 128-row K/V tile (32KB) -> LDS; 8 stage16/thread.
    auto stage = [&](int t128, int buf) {
        const int kt = t128 << 7;
        #pragma unroll
        for (int c = 0; c < 2; c++) {  // row-chunks of 64
            const size_t gK =
                (size_t)(b * 1024 + kt + c * 64 + srow) * 3072 + 1024 + h * 64;
            lds_stage16(qkv + gK + skof,
                        (char*)Ks[buf][0] + c * 4096 + w * 1024);
            lds_stage16(qkv + gK + 32 + skof,
                        (char*)Ks[buf][1] + c * 4096 + w * 1024);
        }
        const size_t gV = ((size_t)bh * 64 + srow) * 1024 + kt;
        #pragma unroll
        for (int sq = 0; sq < 4; sq++)
            lds_stage16(VT + gV + sq * 32 + skof,
                        (char*)Vs[buf][sq] + w * 1024);
    };

    const int nkt = (qblk + 2) >> 1;  // k-tiles of 128
    stage(0, 0);
    for (int t = 0; t < nkt; t++) {
        if (t + 1 < nkt) { stage(t + 1, (t + 1) & 1); wait_vmcnt<8>(); }
        else wait_vmcnt<0>();
        hard_barrier();  // all waves' stage(t) landed (Q loads drained too)
        const int cur = t & 1;
        const int kt = t << 7;

        // QK^T swapped over 128 k-rows: s[nh], k = kt + nh*16 + quad*4 + r
        f32x4 s[8] = {};
        #pragma unroll
        for (int nh = 0; nh < 8; nh++) {
            bf16x8 kb0 = *(const bf16x8*)&Ks[cur][0][(nh * 16 + lr) * 32 + quad * 8];
            bf16x8 kb1 = *(const bf16x8*)&Ks[cur][1][(nh * 16 + lr) * 32 + quad * 8];
            s[nh] = mfma16(kb0, aq0, s[nh]);
            s[nh] = mfma16(kb1, aq1, s[nh]);
        }
        if (kt + 128 > qb) {  // diagonal/partial tile: causal mask (qrow = qb+lr)
            const int qrow = qb + lr;
            #pragma unroll
            for (int nh = 0; nh < 8; nh++)
                #pragma unroll
                for (int r = 0; r < 4; r++) {
                    int kcol = kt + nh * 16 + quad * 4 + r;
                    s[nh][r] = (kcol <= qrow) ? s[nh][r] : -1e30f;
                }
        }
        // row max: 31 local fmax + cross-quad via shfl_xor (lanes sharing lr)
        float mx = fmaxf(fmaxf(s[0][0], s[0][1]), fmaxf(s[0][2], s[0][3]));
        #pragma unroll
        for (int nh = 1; nh < 8; nh++)
            mx = fmaxf(mx, fmaxf(fmaxf(s[nh][0], s[nh][1]),
                                 fmaxf(s[nh][2], s[nh][3])));
        mx = fmaxf(mx, __shfl_xor(mx, 16));
        mx = fmaxf(mx, __shfl_xor(mx, 32));
        // defer-max (T13): rescale only when the row max grew by >8 (log2)
        if (__any(mx > m_i + 8.f)) {
            float mnew = fmaxf(m_i, mx);
            float al = exp2f(m_i - mnew);
            m_i = mnew;
            l_i *= al;
            float alr[4];
            #pragma unroll
            for (int r = 0; r < 4; r++) alr[r] = __shfl(al, quad * 4 + r);
            #pragma unroll
            for (int dt = 0; dt < 4; dt++)
                #pragma unroll
                for (int r = 0; r < 4; r++) oacc[dt][r] *= alr[r];
        }
        float lp = 0.f;
        #pragma unroll
        for (int nh = 0; nh < 8; nh++)
            #pragma unroll
            for (int r = 0; r < 4; r++) {
                float p = exp2f(s[nh][r] - m_i);
                s[nh][r] = p;
                lp += p;
            }
        l_i += lp;
        // PV in two 64-halves; pls reused (intra-wave lgkmcnt ordering only)
        #pragma unroll
        for (int hp = 0; hp < 2; hp++) {
            #pragma unroll
            for (int n4 = 0; n4 < 4; n4++) {
                int nh = hp * 4 + n4;
                uint32x2 pv;
                pv[0] = cvtpk(s[nh][0], s[nh][1]);
                pv[1] = cvtpk(s[nh][2], s[nh][3]);
                *(uint32x2*)&pls[w][lr * 72 + n4 * 16 + quad * 4] = pv;
            }
            bf16x8 ap0 = *(const bf16x8*)&pls[w][lr * 72 + quad * 8];
            bf16x8 ap1 = *(const bf16x8*)&pls[w][lr * 72 + 32 + quad * 8];
            #pragma unroll
            for (int dt = 0; dt < 4; dt++) {
                bf16x8 vb0 = *(const bf16x8*)
                    &Vs[cur][hp * 2][(dt * 16 + lr) * 32 + quad * 8];
                bf16x8 vb1 = *(const bf16x8*)
                    &Vs[cur][hp * 2 + 1][(dt * 16 + lr) * 32 + quad * 8];
                oacc[dt] = mfma16(ap0, vb0, oacc[dt]);
                oacc[dt] = mfma16(ap1, vb1, oacc[dt]);
            }
        }
        lgkm_drain();
        hard_barrier();  // all reads of buf cur done before next overwrite
    }
    // cross-quad finish of l, then broadcast to C-layout rows
    l_i += __shfl_xor(l_i, 16);
    l_i += __shfl_xor(l_i, 32);
    float rl[4];
    #pragma unroll
    for (int r = 0; r < 4; r++) rl[r] = 1.f / __shfl(l_i, quad * 4 + r);
    #pragma unroll
    for (int dt = 0; dt < 4; dt++)
        #pragma unroll
        for (int r = 0; r < 4; r++) {
            int row = b * 1024 + qb + quad * 4 + r;
            int col = h * 64 + dt * 16 + lr;
            O[(size_t)row * 1024 + col] = f2bf_fast(oacc[dt][r] * rl[r]);
        }
}

extern "C" void kernel_launch(void* const* d_in, const int* in_sizes, int n_in,
                              void* d_out, int out_size, void* d_ws, size_t ws_size,
                              hipStream_t stream) {
    const float* x     = (const float*)d_in[0];
    const float* Wqkv  = (const float*)d_in[1];
    const float* Aqkv  = (const float*)d_in[2];
    const float* Bqkv  = (const float*)d_in[3];
    const float* Wproj = (const float*)d_in[4];
    const float* Aproj = (const float*)d_in[5];
    const float* Bproj = (const float*)d_in[6];
    float* out = (float*)d_out;

    char* ws = (char*)d_ws;
    float* h_f32 = (float*)ws;                    ws += (size_t)2048 * 1024 * 4;
    unsigned short* h_bf   = (unsigned short*)ws; ws += (size_t)2048 * 1024 * 2;
    unsigned short* qkv_bf = (unsigned short*)ws; ws += (size_t)2048 * 3072 * 2;
    unsigned short* VT     = (unsigned short*)ws; ws += (size_t)32 * 64 * 1024 * 2;
    unsigned short* O_bf   = (unsigned short*)ws; ws += (size_t)2048 * 1024 * 2;
    unsigned short* WqT8   = (unsigned short*)ws; ws += (size_t)8 * 3072 * 1024 * 2;
    unsigned short* WpT8   = (unsigned short*)ws; ws += (size_t)8 * 1024 * 1024 * 2;

    convert_x<<<2048, 256, 0, stream>>>((const float4*)x, (float4*)h_f32,
                                        (ushort4*)h_bf, 2048 * 1024 / 4);
    // all layers' LoRA merges up front (independent of activations), one dispatch
    merge_T2<<<8192, 256, 0, stream>>>(Wqkv, Aqkv, Bqkv, WqT8,
                                       Wproj, Aproj, Bproj, WpT8);

    for (int l = 0; l < 8; l++) {
        const unsigned short* WqT = WqT8 + (size_t)l * 3072 * 1024;
        const unsigned short* WpT = WpT8 + (size_t)l * 1024 * 1024;
        // qkv GEMM: Q cols pre-scaled log2e/8; V cols written transposed to VT
        gemm_qkv<<<dim3(24, 32), 256, 0, stream>>>(h_bf, WqT, qkv_bf, VT,
                                                   2048, 3072, 1024);
        attn_kernel<<<dim3(16, 32), 256, 0, stream>>>(qkv_bf, VT, O_bf);
        float* outF = (l == 7) ? out : h_f32;
        gemm_bf16_64<<<dim3(16, 32), 256, 0, stream>>>(O_bf, WpT, h_f32, outF,
                                                       h_bf, 2048, 1024, 1024);
    }
}

// Round 15
// 652.391 us; speedup vs baseline: 1.0380x; 1.0380x over previous
//
#include <hip/hip_runtime.h>
#include <hip/hip_bf16.h>

// LoRA transformer: L=8, D=1024, H=16, HD=64, R=16, B=2, S=1024.
// bf16 MFMA everywhere, fp32 residual stream.
// R10: attn + gemm64 double-buffered LDS, one barrier/tile; merge_T2 fused.
// R11: vtrans fused into qkv-GEMM epilogue (V written transposed).
// R12: merge_T2 W tile via DMA; LOG2E folded into Q pre-scale.
// R14: qkv GEMM 64x128 tile, 768 blocks (3/CU exactly), dbuf one-barrier.
// R15: attn defer-max (T13) + v_cvt_pk_bf16_f32 converts.
// R17: swapped QK^T (lane owns one q-row; m/l scalars), shfl_xor reductions,
// packed P LDS round-trip (4x ds_write_b64 + 2x ds_read_b128, no barrier).
// R18 (REGRESSED +93us): no-staging attn -> reverted.
// R19: attn KVBLK=128 (halved barrier drains), dbuf DMA staging kept. BEST: 655us.
// R20 (REGRESSED +11us): merge 4-way split + proj BK=128 -> reverted.
// R21 (REGRESSED +22us): counted-vmcnt raw-barrier graft on 2-phase loops ->
// reverted (guide regime-gate: T4 is null/negative without the 8-phase
// structure; sched_barrier fences pinned the compiler's scheduling, m141).
// R22: revert to R19 verbatim. Structural note: loop = 172 GFLOP / ~583us =
// 294 TF effective, within ~10% of the m102 shape-curve plateau (~320 TF at
// N~2048-equivalent) for 2-phase LDS-staged structures; 256²/8-phase needs
// >=256² tiles -> <=96 blocks on 256 CUs at these shapes (worse). merge_T2
// pinned at multi-pipe ~67us floor (4 structurally distinct rewrites, invariant).

typedef unsigned short ushort_t;
typedef __attribute__((ext_vector_type(8))) short bf16x8;
typedef __attribute__((ext_vector_type(4))) float f32x4;
typedef __attribute__((ext_vector_type(2))) unsigned int uint32x2;

__device__ __forceinline__ unsigned short f2bf(float f) {
    union { float f; unsigned int u; } x; x.f = f;
    unsigned int r = x.u + 0x7fffu + ((x.u >> 16) & 1u);  // RNE
    return (unsigned short)(r >> 16);
}

// single-instruction bf16 convert (RNE), result in low 16 bits
__device__ __forceinline__ unsigned short f2bf_fast(float f) {
    unsigned int r;
    asm("v_cvt_pk_bf16_f32 %0, %1, %2" : "=v"(r) : "v"(f), "v"(0.f));
    return (unsigned short)r;
}

// pack two f32 -> {bf16(lo), bf16(hi)} in one dword
__device__ __forceinline__ unsigned int cvtpk(float lo, float hi) {
    unsigned int r;
    asm("v_cvt_pk_bf16_f32 %0, %1, %2" : "=v"(r) : "v"(lo), "v"(hi));
    return r;
}

__device__ __forceinline__ f32x4 mfma16(bf16x8 a, bf16x8 b, f32x4 c) {
    return __builtin_amdgcn_mfma_f32_16x16x32_bf16(a, b, c, 0, 0, 0);
}

typedef const __attribute__((address_space(1))) unsigned int* gas_ptr;
typedef __attribute__((address_space(3))) unsigned int* las_ptr;
// async global->LDS, 16B/lane; LDS dest = wave-uniform base + lane*16 (m104/m108)
__device__ __forceinline__ void lds_stage16(const void* g, void* l) {
    __builtin_amdgcn_global_load_lds((gas_ptr)(unsigned long long)g,
                                     (las_ptr)(unsigned int)(unsigned long long)l,
                                     16, 0, 0);
}

// ---------------- x -> (h_f32 copy, h_bf16) ----------------
__global__ __launch_bounds__(256) void convert_x(
    const float4* __restrict__ in, float4* __restrict__ outF,
    ushort4* __restrict__ outB, int n4) {
    int i = blockIdx.x * 256 + threadIdx.x;
    if (i < n4) {
        float4 v = in[i];
        outF[i] = v;
        ushort4 o;
        o.x = f2bf(v.x); o.y = f2bf(v.y); o.z = f2bf(v.z); o.w = f2bf(v.w);
        outB[i] = o;
    }
}

// ------------- LoRA merge + transpose, qkv + proj in ONE dispatch -------------
// blocks 0..6143: qkv (24x32x8); blocks 6144..8191: proj (8x32x8)
// WT[z][n][k] = bf16(W[z][k][n] + A[z][k][:] . B[z][:][n])
// W tile -> LDS via DMA; lora computed in transposed layout; B column in regs.
__global__ __launch_bounds__(256) void merge_T2(
    const float* __restrict__ Wq, const float* __restrict__ Aq,
    const float* __restrict__ Bq, unsigned short* __restrict__ WTq,
    const float* __restrict__ Wp, const float* __restrict__ Ap,
    const float* __restrict__ Bp, unsigned short* __restrict__ WTp) {
    __shared__ float Asl[32][17];                 // A tile (32 rows x 16), +1 pad
    __shared__ __align__(16) float tW[32 * 128];  // W tile, DMA'd, linear
    int bid = blockIdx.x;
    const float *W, *A, *Bm;
    unsigned short* WT;
    int N, bx, by, bz;
    if (bid < 6144) {
        N = 3072; bx = bid % 24; int u = bid / 24; by = u & 31; bz = u >> 5;
        W = Wq; A = Aq; Bm = Bq; WT = WTq;
    } else {
        bid -= 6144;
        N = 1024; bx = bid & 7; int u = bid >> 3; by = u & 31; bz = u >> 5;
        W = Wp; A = Ap; Bm = Bp; WT = WTp;
    }
    W  += (size_t)bz * 1024 * N;
    A  += (size_t)bz * 1024 * 16;
    Bm += (size_t)bz * 16 * N;
    WT += (size_t)bz * N * 1024;
    const int j0 = bx * 128, i0 = by * 32;
    const int tid = threadIdx.x;
    const int w = tid >> 6, lane = tid & 63;

    // DMA W tile (32x128 f32 = 16KB) -> LDS. 4 stage16 per thread.
    #pragma unroll
    for (int s = 0; s < 4; s++) {
        int w4s = w * 4 + s;
        int tr = w4s * 2 + (lane >> 5);
        lds_stage16(W + (size_t)(i0 + tr) * N + j0 + (lane & 31) * 4,
                    (char*)tW + w4s * 1024);
    }
    // Stage A tile cooperatively: 512 floats, 128 threads x float4, coalesced.
    if (tid < 128) {
        int r = tid >> 2, c4 = (tid & 3) * 4;
        float4 a = *(const float4*)&A[(size_t)(i0 + r) * 16 + c4];
        Asl[r][c4 + 0] = a.x; Asl[r][c4 + 1] = a.y;
        Asl[r][c4 + 2] = a.z; Asl[r][c4 + 3] = a.w;
    }
    // B column for this thread's output row: 16 independent dwords, L2-hot.
    const int jj = tid >> 1, half = tid & 1;
    float bcol[16];
    #pragma unroll
    for (int r = 0; r < 16; r++)
        bcol[r] = Bm[(size_t)r * N + j0 + jj];
    __builtin_amdgcn_sched_barrier(0);
    __syncthreads();  // drains W DMA (vmcnt) + A stage

    // 16 output values: rows i0+half*16+c, col j0+jj; transposed store.
    bf16x8 o0, o1;
    #pragma unroll
    for (int c = 0; c < 16; c++) {
        int rloc = half * 16 + c;
        float v = tW[rloc * 128 + jj];             // bank=jj%32: 2-way, free
        #pragma unroll
        for (int r = 0; r < 16; r++)
            v += Asl[rloc][r] * bcol[r];           // Asl: 2-addr broadcast
        unsigned short b = f2bf(v);
        if (c < 8) o0[c] = (short)b; else o1[c - 8] = (short)b;
    }
    unsigned short* dst = &WT[(size_t)(j0 + jj) * 1024 + i0 + half * 16];
    *(bf16x8*)dst = o0;
    *(bf16x8*)(dst + 8) = o1;
}

// --- qkv GEMM: 64x128 tile, dbuf BK=64, one barrier/tile; 768 blocks (3/CU) ---
// V-blocks (n0>=2048) write VT transposed directly.
__global__ __launch_bounds__(256) void gemm_qkv(
    const unsigned short* __restrict__ A,   // [M][K] h_bf
    const unsigned short* __restrict__ BT,  // [N][K] merged qkv weights^T
    unsigned short* __restrict__ outB,      // bf16 out (Q,K regions)
    unsigned short* __restrict__ VT,        // [32][64][1024] transposed V out
    int M, int N, int K) {
    __shared__ __align__(16) unsigned short As[2][2][64 * 32];   // [buf][h]
    __shared__ __align__(16) unsigned short Bs[2][2][128 * 32];  // [buf][h]
    const int tid = threadIdx.x;
    const int m0 = blockIdx.y * 64, n0 = blockIdx.x * 128;
    const int w = tid >> 6, lane = tid & 63;
    const int wm = (w >> 1) * 32, wn = (w & 1) * 64;
    const int lr = lane & 15, quad = lane >> 4;
    const int srowA = w * 16 + (lane >> 2);
    const int skof = (lane & 3) * 8;

    f32x4 acc[2][4] = {};

    auto stage = [&](int k0, int buf) {
        #pragma unroll
        for (int h = 0; h < 2; h++) {
            lds_stage16(A + (size_t)(m0 + srowA) * K + k0 + h * 32 + skof,
                        (char*)As[buf][h] + w * 1024);
            #pragma unroll
            for (int s = 0; s < 2; s++) {
                int srowB = w * 32 + s * 16 + (lane >> 2);
                lds_stage16(BT + (size_t)(n0 + srowB) * K + k0 + h * 32 + skof,
                            (char*)Bs[buf][h] + (w * 2 + s) * 1024);
            }
        }
    };

    const int nk = K >> 6;
    stage(0, 0);
    for (int t = 0; t < nk; t++) {
        __syncthreads();  // drains stage(t) [vmcnt(0)] + prior reads of buf t&1
        if (t + 1 < nk) stage((t + 1) << 6, (t + 1) & 1);
        const int cur = t & 1;
        #pragma unroll
        for (int h = 0; h < 2; h++) {
            bf16x8 af[2], bfr[4];
            #pragma unroll
            for (int i = 0; i < 2; i++)
                af[i] = *(const bf16x8*)&As[cur][h][(wm + i * 16 + lr) * 32 + quad * 8];
            #pragma unroll
            for (int j = 0; j < 4; j++)
                bfr[j] = *(const bf16x8*)&Bs[cur][h][(wn + j * 16 + lr) * 32 + quad * 8];
            #pragma unroll
            for (int i = 0; i < 2; i++)
                #pragma unroll
                for (int j = 0; j < 4; j++)
                    acc[i][j] = mfma16(af[i], bfr[j], acc[i][j]);
        }
    }
    if (n0 < 2048) {  // Q,K regions -> qkv_bf (Q cols pre-scaled by log2e/8)
        #pragma unroll
        for (int i = 0; i < 2; i++)
            #pragma unroll
            for (int j = 0; j < 4; j++)
                #pragma unroll
                for (int r = 0; r < 4; r++) {
                    int row = m0 + wm + i * 16 + quad * 4 + r;
                    int col = n0 + wn + j * 16 + lr;
                    float v = acc[i][j][r];
                    if (col < 1024) v *= 0.125f * 1.44269504f;  // 1/sqrt(64)*log2e
                    outB[(size_t)row * N + col] = f2bf(v);
                }
    } else {  // V region -> VT[b*1024+hd][s], 4 consecutive s per thread
        const int b = m0 >> 10;
        #pragma unroll
        for (int i = 0; i < 2; i++) {
            int row0 = m0 + wm + i * 16 + quad * 4;
            int s = row0 & 1023;
            #pragma unroll
            for (int j = 0; j < 4; j++) {
                int hd = n0 - 2048 + wn + j * 16 + lr;
                ushort4 o;
                o.x = f2bf(acc[i][j][0]); o.y = f2bf(acc[i][j][1]);
                o.z = f2bf(acc[i][j][2]); o.w = f2bf(acc[i][j][3]);
                *(ushort4*)&VT[((size_t)b * 1024 + hd) * 1024 + s] = o;
            }
        }
    }
}

// ------------- GEMM 64x64 + residual: dbuf LDS, one barrier/tile -------------
__global__ __launch_bounds__(256) void gemm_bf16_64(
    const unsigned short* __restrict__ A,   // [M][K]
    const unsigned short* __restrict__ BT,  // [N][K]
    const float* __restrict__ res,          // [M][N] residual
    float* __restrict__ outF,               // fp32 out
    unsigned short* __restrict__ outB,      // bf16 out
    int M, int N, int K) {
    __shared__ __align__(16) unsigned short As[2][2][64 * 32];  // [buf][half]
    __shared__ __align__(16) unsigned short Bs[2][2][64 * 32];
    const int tid = threadIdx.x;
    const int m0 = blockIdx.y * 64, n0 = blockIdx.x * 64;
    const int w = tid >> 6, lane = tid & 63;
    const int wm = (w >> 1) * 32, wn = (w & 1) * 32;
    const int lr = lane & 15, quad = lane >> 4;
    const int srow = w * 16 + (lane >> 2);
    const int skof = (lane & 3) * 8;

    f32x4 acc[2][2] = {};

    auto stage = [&](int k0, int buf) {
        #pragma unroll
        for (int h = 0; h < 2; h++) {
            lds_stage16(A  + (size_t)(m0 + srow) * K + k0 + h * 32 + skof,
                        (char*)As[buf][h] + w * 1024);
            lds_stage16(BT + (size_t)(n0 + srow) * K + k0 + h * 32 + skof,
                        (char*)Bs[buf][h] + w * 1024);
        }
    };

    const int nk = K >> 6;
    stage(0, 0);
    for (int t = 0; t < nk; t++) {
        __syncthreads();  // drains stage(t) [vmcnt(0)] + prior reads of buf t&1
        if (t + 1 < nk) stage((t + 1) << 6, (t + 1) & 1);
        const int cur = t & 1;
        #pragma unroll
        for (int h = 0; h < 2; h++) {
            bf16x8 af[2], bfr[2];
            #pragma unroll
            for (int i = 0; i < 2; i++) {
                af[i]  = *(const bf16x8*)&As[cur][h][(wm + i * 16 + lr) * 32 + quad * 8];
                bfr[i] = *(const bf16x8*)&Bs[cur][h][(wn + i * 16 + lr) * 32 + quad * 8];
            }
            #pragma unroll
            for (int i = 0; i < 2; i++)
                #pragma unroll
                for (int j = 0; j < 2; j++)
                    acc[i][j] = mfma16(af[i], bfr[j], acc[i][j]);
        }
    }
    #pragma unroll
    for (int i = 0; i < 2; i++)
        #pragma unroll
        for (int j = 0; j < 2; j++)
            #pragma unroll
            for (int r = 0; r < 4; r++) {
                int row = m0 + wm + i * 16 + quad * 4 + r;
                int col = n0 + wn + j * 16 + lr;
                float v = acc[i][j][r] + res[(size_t)row * N + col];
                if (outF) outF[(size_t)row * N + col] = v;
                if (outB) outB[(size_t)row * N + col] = f2bf(v);
            }
}

// ------- Flash attention: dbuf DMA staging, KVBLK=128, one barrier/tile -------
// 512 blocks, one 64-row q-block each; qblk = bh<16 ? x : 15-x.
// Scores arrive already in log2 domain (Q pre-scaled by log2e/8 in gemm_qkv).
// Swapped QK^T: s = mfma(K,Q) = S^T; lane owns q = qb+lr, k = nh*16+quad*4+r.
// P repack via packed per-wave LDS round-trip, PV in two 64-halves.
__global__ __launch_bounds__(256) void attn_kernel(
    const unsigned short* __restrict__ qkv,  // [2048][3072]
    const unsigned short* __restrict__ VT,   // [32][64][1024]
    unsigned short* __restrict__ O) {        // [2048][1024]
    __shared__ __align__(16) unsigned short Ks[2][2][128 * 32];  // [buf][dhalf][row][d32]
    __shared__ __align__(16) unsigned short Vs[2][4][64 * 32];   // [buf][squarter][d][s32]
    __shared__ __align__(16) unsigned short pls[4][16 * 72];     // P half-rows, stride 72
    const int tid = threadIdx.x;
    const int w = tid >> 6, lane = tid & 63;
    const int lr = lane & 15, quad = lane >> 4;
    const int bh = blockIdx.y, b = bh >> 4, h = bh & 15;
    const int qblk = (bh < 16) ? blockIdx.x : (15 - blockIdx.x);
    const int qb = qblk * 64 + w * 16;
    const int srow = w * 16 + (lane >> 2);
    const int skof = (lane & 3) * 8;

    const size_t rowQ = (size_t)(b * 1024 + qb + lr) * 3072 + h * 64;
    bf16x8 aq0 = *(const bf16x8*)&qkv[rowQ + quad * 8];
    bf16x8 aq1 = *(const bf16x8*)&qkv[rowQ + 32 + quad * 8];

    float m_i = -1e30f, l_i = 0.f;   // scalars: lane owns one q-row (q = qb+lr)
    f32x4 oacc[4] = {};

    // Stage one 128-row K/V tile (32KB) -> LDS; 8 stage16/thread.
    auto stage = [&](int t128, int buf) {
        const int kt = t128 << 7;
        #pragma unroll
        for (int c = 0; c < 2; c++) {  // row-chunks of 64
            const size_t gK =
                (size_t)(b * 1024 + kt + c * 64 + srow) * 3072 + 1024 + h * 64;
            lds_stage16(qkv + gK + skof,
                        (char*)Ks[buf][0] + c * 4096 + w * 1024);
            lds_stage16(qkv + gK + 32 + skof,
                        (char*)Ks[buf][1] + c * 4096 + w * 1024);
        }
        const size_t gV = ((size_t)bh * 64 + srow) * 1024 + kt;
        #pragma unroll
        for (int sq = 0; sq < 4; sq++)
            lds_stage16(VT + gV + sq * 32 + skof,
                        (char*)Vs[buf][sq] + w * 1024);
    };

    const int nkt = (qblk + 2) >> 1;  // k-tiles of 128
    stage(0, 0);
    for (int t = 0; t < nkt; t++) {
        __syncthreads();  // drains stage(t) [vmcnt(0)]; prior reads of buf done
        if (t + 1 < nkt) stage(t + 1, (t + 1) & 1);
        const int cur = t & 1;
        const int kt = t << 7;

        // QK^T swapped over 128 k-rows: s[nh], k = kt + nh*16 + quad*4 + r
        f32x4 s[8] = {};
        #pragma unroll
        for (int nh = 0; nh < 8; nh++) {
            bf16x8 kb0 = *(const bf16x8*)&Ks[cur][0][(nh * 16 + lr) * 32 + quad * 8];
            bf16x8 kb1 = *(const bf16x8*)&Ks[cur][1][(nh * 16 + lr) * 32 + quad * 8];
            s[nh] = mfma16(kb0, aq0, s[nh]);
            s[nh] = mfma16(kb1, aq1, s[nh]);
        }
        if (kt + 128 > qb) {  // diagonal/partial tile: causal mask (qrow = qb+lr)
            const int qrow = qb + lr;
            #pragma unroll
            for (int nh = 0; nh < 8; nh++)
                #pragma unroll
                for (int r = 0; r < 4; r++) {
                    int kcol = kt + nh * 16 + quad * 4 + r;
                    s[nh][r] = (kcol <= qrow) ? s[nh][r] : -1e30f;
                }
        }
        // row max: 31 local fmax + cross-quad via shfl_xor (lanes sharing lr)
        float mx = fmaxf(fmaxf(s[0][0], s[0][1]), fmaxf(s[0][2], s[0][3]));
        #pragma unroll
        for (int nh = 1; nh < 8; nh++)
            mx = fmaxf(mx, fmaxf(fmaxf(s[nh][0], s[nh][1]),
                                 fmaxf(s[nh][2], s[nh][3])));
        mx = fmaxf(mx, __shfl_xor(mx, 16));
        mx = fmaxf(mx, __shfl_xor(mx, 32));
        // defer-max (T13): rescale only when the row max grew by >8 (log2)
        if (__any(mx > m_i + 8.f)) {
            float mnew = fmaxf(m_i, mx);
            float al = exp2f(m_i - mnew);
            m_i = mnew;
            l_i *= al;
            float alr[4];
            #pragma unroll
            for (int r = 0; r < 4; r++) alr[r] = __shfl(al, quad * 4 + r);
            #pragma unroll
            for (int dt = 0; dt < 4; dt++)
                #pragma unroll
                for (int r = 0; r < 4; r++) oacc[dt][r] *= alr[r];
        }
        float lp = 0.f;
        #pragma unroll
        for (int nh = 0; nh < 8; nh++)
            #pragma unroll
            for (int r = 0; r < 4; r++) {
                float p = exp2f(s[nh][r] - m_i);
                s[nh][r] = p;
                lp += p;
            }
        l_i += lp;
        // PV in two 64-halves; pls reused (intra-wave lgkmcnt ordering only)
        #pragma unroll
        for (int hp = 0; hp < 2; hp++) {
            #pragma unroll
            for (int n4 = 0; n4 < 4; n4++) {
                int nh = hp * 4 + n4;
                uint32x2 pv;
                pv[0] = cvtpk(s[nh][0], s[nh][1]);
                pv[1] = cvtpk(s[nh][2], s[nh][3]);
                *(uint32x2*)&pls[w][lr * 72 + n4 * 16 + quad * 4] = pv;
            }
            bf16x8 ap0 = *(const bf16x8*)&pls[w][lr * 72 + quad * 8];
            bf16x8 ap1 = *(const bf16x8*)&pls[w][lr * 72 + 32 + quad * 8];
            #pragma unroll
            for (int dt = 0; dt < 4; dt++) {
                bf16x8 vb0 = *(const bf16x8*)
                    &Vs[cur][hp * 2][(dt * 16 + lr) * 32 + quad * 8];
                bf16x8 vb1 = *(const bf16x8*)
                    &Vs[cur][hp * 2 + 1][(dt * 16 + lr) * 32 + quad * 8];
                oacc[dt] = mfma16(ap0, vb0, oacc[dt]);
                oacc[dt] = mfma16(ap1, vb1, oacc[dt]);
            }
        }
    }
    // cross-quad finish of l, then broadcast to C-layout rows
    l_i += __shfl_xor(l_i, 16);
    l_i += __shfl_xor(l_i, 32);
    float rl[4];
    #pragma unroll
    for (int r = 0; r < 4; r++) rl[r] = 1.f / __shfl(l_i, quad * 4 + r);
    #pragma unroll
    for (int dt = 0; dt < 4; dt++)
        #pragma unroll
        for (int r = 0; r < 4; r++) {
            int row = b * 1024 + qb + quad * 4 + r;
            int col = h * 64 + dt * 16 + lr;
            O[(size_t)row * 1024 + col] = f2bf_fast(oacc[dt][r] * rl[r]);
        }
}

extern "C" void kernel_launch(void* const* d_in, const int* in_sizes, int n_in,
                              void* d_out, int out_size, void* d_ws, size_t ws_size,
                              hipStream_t stream) {
    const float* x     = (const float*)d_in[0];
    const float* Wqkv  = (const float*)d_in[1];
    const float* Aqkv  = (const float*)d_in[2];
    const float* Bqkv  = (const float*)d_in[3];
    const float* Wproj = (const float*)d_in[4];
    const float* Aproj = (const float*)d_in[5];
    const float* Bproj = (const float*)d_in[6];
    float* out = (float*)d_out;

    char* ws = (char*)d_ws;
    float* h_f32 = (float*)ws;                    ws += (size_t)2048 * 1024 * 4;
    unsigned short* h_bf   = (unsigned short*)ws; ws += (size_t)2048 * 1024 * 2;
    unsigned short* qkv_bf = (unsigned short*)ws; ws += (size_t)2048 * 3072 * 2;
    unsigned short* VT     = (unsigned short*)ws; ws += (size_t)32 * 64 * 1024 * 2;
    unsigned short* O_bf   = (unsigned short*)ws; ws += (size_t)2048 * 1024 * 2;
    unsigned short* WqT8   = (unsigned short*)ws; ws += (size_t)8 * 3072 * 1024 * 2;
    unsigned short* WpT8   = (unsigned short*)ws; ws += (size_t)8 * 1024 * 1024 * 2;

    convert_x<<<2048, 256, 0, stream>>>((const float4*)x, (float4*)h_f32,
                                        (ushort4*)h_bf, 2048 * 1024 / 4);
    // all layers' LoRA merges up front (independent of activations), one dispatch
    merge_T2<<<8192, 256, 0, stream>>>(Wqkv, Aqkv, Bqkv, WqT8,
                                       Wproj, Aproj, Bproj, WpT8);

    for (int l = 0; l < 8; l++) {
        const unsigned short* WqT = WqT8 + (size_t)l * 3072 * 1024;
        const unsigned short* WpT = WpT8 + (size_t)l * 1024 * 1024;
        // qkv GEMM: Q cols pre-scaled log2e/8; V cols written transposed to VT
        gemm_qkv<<<dim3(24, 32), 256, 0, stream>>>(h_bf, WqT, qkv_bf, VT,
                                                   2048, 3072, 1024);
        attn_kernel<<<dim3(16, 32), 256, 0, stream>>>(qkv_bf, VT, O_bf);
        float* outF = (l == 7) ? out : h_f32;
        gemm_bf16_64<<<dim3(16, 32), 256, 0, stream>>>(O_bf, WpT, h_f32, outF,
                                                       h_bf, 2048, 1024, 1024);
    }
}